// Round 7
// baseline (275.263 us; speedup 1.0000x reference)
//
#include <hip/hip_runtime.h>

typedef unsigned short u16;
typedef __bf16 bf16x8 __attribute__((ext_vector_type(8)));
typedef float f32x16 __attribute__((ext_vector_type(16)));

__device__ __forceinline__ u16 f2bf(float f) {
    unsigned u = __builtin_bit_cast(unsigned, f);
    u += 0x7fffu + ((u >> 16) & 1u);
    return (u16)(u >> 16);
}

#define GLDS16(g, l) __builtin_amdgcn_global_load_lds( \
    (const __attribute__((address_space(1))) void*)(g), \
    (__attribute__((address_space(3))) void*)(l), 16, 0, 0)

#define QK_SCALE 0.044194173824159216f

// ---------------------------------------------------------------------------
// Weight conversion: fp32 -> bf16 (Wq|Wk|Wv stacked, Wp), concat biases.
// Wq and bq pre-scaled by C^-1/2 so QK^T comes out pre-scaled.
// ---------------------------------------------------------------------------
__global__ __launch_bounds__(256) void convert_kernel(
    const float* __restrict__ Wq, const float* __restrict__ Wk,
    const float* __restrict__ Wv, const float* __restrict__ Wp,
    const float* __restrict__ bq, const float* __restrict__ bk,
    const float* __restrict__ bv,
    u16* __restrict__ Wqkv, u16* __restrict__ Wpb, float* __restrict__ bqkv)
{
    int idx = blockIdx.x * 256 + threadIdx.x;  // 4096 * 256 = 1048576
    if (idx < 786432) {
        int which = idx >> 18;
        int off   = idx & 262143;
        if (which == 0)
            Wqkv[idx] = f2bf(Wq[off] * QK_SCALE);
        else
            Wqkv[idx] = f2bf(((which == 1) ? Wk : Wv)[off]);
    } else {
        int off = idx - 786432;
        Wpb[off] = f2bf(Wp[off]);
    }
    if (idx < 1536) {
        float bvv = (idx < 512) ? bq[idx] * QK_SCALE
                  : (idx < 1024) ? bk[idx & 511] : bv[idx & 511];
        bqkv[idx] = bvv;
    }
}

// ---------------------------------------------------------------------------
// GroupNorm: x [B,C,T] fp32 -> h_t [B,T,C] bf16.  One block per (b, group).
// ---------------------------------------------------------------------------
__global__ __launch_bounds__(256) void gn_kernel(
    const float* __restrict__ x, const float* __restrict__ gamma,
    const float* __restrict__ beta, u16* __restrict__ ht)
{
    const int g = blockIdx.x, b = blockIdx.y, tid = threadIdx.x;
    const float* xg = x + ((size_t)b * 512 + (size_t)g * 16) * 1024;

    float s = 0.f, s2 = 0.f;
    const float4* x4 = (const float4*)xg;
    #pragma unroll 4
    for (int i = tid; i < 4096; i += 256) {
        float4 v = x4[i];
        s  += v.x + v.y + v.z + v.w;
        s2 += v.x * v.x + v.y * v.y + v.z * v.z + v.w * v.w;
    }
    #pragma unroll
    for (int off = 32; off; off >>= 1) {
        s  += __shfl_down(s, off);
        s2 += __shfl_down(s2, off);
    }
    __shared__ float rs[4], rs2[4];
    __shared__ float stat[2];
    const int w = tid >> 6;
    if ((tid & 63) == 0) { rs[w] = s; rs2[w] = s2; }
    __syncthreads();
    if (tid == 0) {
        float S  = rs[0] + rs[1] + rs[2] + rs[3];
        float S2 = rs2[0] + rs2[1] + rs2[2] + rs2[3];
        float mean = S * (1.f / 16384.f);
        float var  = S2 * (1.f / 16384.f) - mean * mean;
        stat[0] = mean;
        stat[1] = rsqrtf(var + 1e-5f);
    }
    __syncthreads();
    const float mean = stat[0], rstd = stat[1];

    float ga[16], be[16];
    #pragma unroll
    for (int ci = 0; ci < 16; ci++) {
        ga[ci] = gamma[g * 16 + ci];
        be[ci] = beta[g * 16 + ci];
    }
    for (int t = tid; t < 1024; t += 256) {
        u16 yv[16];
        #pragma unroll
        for (int ci = 0; ci < 16; ci++) {
            float v = xg[ci * 1024 + t];
            yv[ci] = f2bf((v - mean) * rstd * ga[ci] + be[ci]);
        }
        uint4* dst = (uint4*)(ht + ((size_t)b * 1024 + t) * 512 + g * 16);
        dst[0] = ((const uint4*)yv)[0];
        dst[1] = ((const uint4*)yv)[1];
    }
}

// ---------------------------------------------------------------------------
// Row softmax over bf16 scores [16384 rows, 1024 cols], in place.
// One wave per row, 16 elems per lane, butterfly reductions, no LDS.
// ---------------------------------------------------------------------------
__global__ __launch_bounds__(256) void softmax_kernel(u16* __restrict__ scores)
{
    const int row  = blockIdx.x * 4 + (threadIdx.x >> 6);
    const int lane = threadIdx.x & 63;
    u16* p = scores + (size_t)row * 1024 + lane * 16;

    uint4 w0 = ((const uint4*)p)[0];
    uint4 w1 = ((const uint4*)p)[1];
    unsigned wd[8] = {w0.x, w0.y, w0.z, w0.w, w1.x, w1.y, w1.z, w1.w};
    float v[16];
    #pragma unroll
    for (int i = 0; i < 8; i++) {
        v[2 * i]     = __builtin_bit_cast(float, wd[i] << 16);
        v[2 * i + 1] = __builtin_bit_cast(float, wd[i] & 0xffff0000u);
    }
    float m = v[0];
    #pragma unroll
    for (int i = 1; i < 16; i++) m = fmaxf(m, v[i]);
    #pragma unroll
    for (int off = 1; off < 64; off <<= 1) m = fmaxf(m, __shfl_xor(m, off));

    float s = 0.f;
    #pragma unroll
    for (int i = 0; i < 16; i++) { v[i] = __expf(v[i] - m); s += v[i]; }
    #pragma unroll
    for (int off = 1; off < 64; off <<= 1) s += __shfl_xor(s, off);
    const float inv = 1.0f / s;

    #pragma unroll
    for (int i = 0; i < 8; i++) {
        unsigned lo = f2bf(v[2 * i] * inv);
        unsigned hi = f2bf(v[2 * i + 1] * inv);
        wd[i] = lo | (hi << 16);
    }
    ((uint4*)p)[0] = make_uint4(wd[0], wd[1], wd[2], wd[3]);
    ((uint4*)p)[1] = make_uint4(wd[4], wd[5], wd[6], wd[7]);
}

// ---------------------------------------------------------------------------
// Wide NT GEMM: C[m][n] = sum_k A[m][k]*B[n][k], block tile 128m x 256n,
// BK=64, single-buffer LDS (48 KB -> 3 blocks/CU), 2-barrier K-loop.
// 4 waves (2x2), each wave 64m x 128n = 2x4 frags of 32x32x16 MFMA
// (32 MFMA per wave per iteration -- 2x the 128x128 shape at the same
// per-iteration latency quantum).
// Dual-xor swizzle (R6-verified, 0 conflicts):
//   write: row r slab s, slot sc holds chunk sc^key, key=srow^((2s+(srow>>2))&7)
//   read:  chunk cidx at slot cidx^rkey, rkey=(l31&7)^((l31>>2)&7)
// MODE 0: qkv -> q,k bf16 row-major [B,T,C]; v bf16 [B,C,S]; +bias[n]
// MODE 1: scores -> bf16 [B,T(n),S(m)] (ushort4 along m)
// ---------------------------------------------------------------------------
template <int MODE>
__global__ __launch_bounds__(256) void gemm_wide(
    const u16* __restrict__ A, const u16* __restrict__ B,
    size_t strideA, size_t strideB, int lda, int ldb, int K,
    u16* __restrict__ o0, u16* __restrict__ o1, u16* __restrict__ o2,
    const float* __restrict__ bias)
{
    __shared__ u16 As[128 * 64];   // 16 KB
    __shared__ u16 Bs[256 * 64];   // 32 KB

    const int tid   = threadIdx.x;
    const int lane  = tid & 63;
    const int wave  = tid >> 6;
    const int wm    = (wave >> 1) * 64;     // wave m-offset (64 rows)
    const int wn    = (wave & 1) * 128;     // wave n-offset (128 cols)
    const int l31   = lane & 31;
    const int khalf = lane >> 5;
    const int b     = blockIdx.z;

    const u16* Ab = A + (size_t)b * strideA + (size_t)blockIdx.y * 128 * lda;
    const u16* Bb = B + (size_t)b * strideB + (size_t)blockIdx.x * 256 * ldb;

    const int srow = lane >> 3;     // 0..7
    const int sc   = lane & 7;      // LDS chunk slot
    const int rkey = (l31 & 7) ^ ((l31 >> 2) & 7);

    f32x16 acc[2][4] = {};

    for (int k0 = 0; k0 < K; k0 += 64) {
        __syncthreads();
        #pragma unroll
        for (int s = 0; s < 4; s++) {          // A: 128 rows, 32/wave
            const int r   = wave * 32 + s * 8 + srow;
            const int key = srow ^ ((2 * s + (srow >> 2)) & 7);
            GLDS16(Ab + (size_t)r * lda + k0 + ((sc ^ key) * 8),
                   As + r * 64 + sc * 8);
        }
        #pragma unroll
        for (int s = 0; s < 8; s++) {          // B: 256 rows, 64/wave
            const int r   = wave * 64 + s * 8 + srow;
            const int key = srow ^ ((2 * s + (srow >> 2)) & 7);
            GLDS16(Bb + (size_t)r * ldb + k0 + ((sc ^ key) * 8),
                   Bs + r * 64 + sc * 8);
        }
        __syncthreads();

        #pragma unroll
        for (int ks = 0; ks < 4; ks++) {
            const int slot = ((ks * 2 + khalf) ^ rkey) * 8;
            bf16x8 af[2], bf[4];
            #pragma unroll
            for (int i = 0; i < 2; i++)
                af[i] = *(const bf16x8*)(As + (wm + i * 32 + l31) * 64 + slot);
            #pragma unroll
            for (int j = 0; j < 4; j++)
                bf[j] = *(const bf16x8*)(Bs + (wn + j * 32 + l31) * 64 + slot);
            #pragma unroll
            for (int i = 0; i < 2; i++)
                #pragma unroll
                for (int j = 0; j < 4; j++)
                    acc[i][j] = __builtin_amdgcn_mfma_f32_32x32x16_bf16(
                        af[i], bf[j], acc[i][j], 0, 0, 0);
        }
    }

    // Epilogue. C/D: col = lane&31, row = (reg&3) + 8*(reg>>2) + 4*(lane>>5)
    const int m_base = blockIdx.y * 128 + wm + 4 * khalf;
    const int n_base = blockIdx.x * 256 + wn + l31;

    #pragma unroll
    for (int i = 0; i < 2; i++) {
        #pragma unroll
        for (int j = 0; j < 4; j++) {
            const int n = n_base + j * 32;
            float bv = 0.f;
            if (MODE == 0) bv = bias[n];
            #pragma unroll
            for (int g = 0; g < 4; g++) {
                const int m = m_base + i * 32 + 8 * g;
                const float a0 = acc[i][j][4 * g]     + bv;
                const float a1 = acc[i][j][4 * g + 1] + bv;
                const float a2 = acc[i][j][4 * g + 2] + bv;
                const float a3 = acc[i][j][4 * g + 3] + bv;
                if (MODE == 0) {
                    if (n < 1024) {          // q or k: row-major [.,C], scalar
                        u16* dst = (n < 512) ? o0 : o1;
                        const int nn = n & 511;
                        dst[((size_t)b * 1024 + m) * 512 + nn]     = f2bf(a0);
                        dst[((size_t)b * 1024 + m + 1) * 512 + nn] = f2bf(a1);
                        dst[((size_t)b * 1024 + m + 2) * 512 + nn] = f2bf(a2);
                        dst[((size_t)b * 1024 + m + 3) * 512 + nn] = f2bf(a3);
                    } else {                 // v: [B,C,S], ushort4 along m
                        ushort4 hv = {f2bf(a0), f2bf(a1), f2bf(a2), f2bf(a3)};
                        *(ushort4*)(o2 + ((size_t)b * 512 + (n - 1024)) * 1024 + m) = hv;
                    }
                } else {                     // scores[b][t=n][s=m] bf16
                    ushort4 hv = {f2bf(a0), f2bf(a1), f2bf(a2), f2bf(a3)};
                    *(ushort4*)(o0 + ((size_t)b * 1024 + n) * 1024 + m) = hv;
                }
            }
        }
    }
}

// ---------------------------------------------------------------------------
// 128x128 NT GEMM (R3 structure, conflict-free swizzle), single-buffer.
// MODE 2: pv -> h2 bf16 [B,T(n),C(m)]   (ushort4 along m)
// MODE 3: proj -> fp32 d_out[B,C,T] = acc + bias[n] + x  (float4 along m)
// ---------------------------------------------------------------------------
template <int MODE>
__global__ __launch_bounds__(256) void gemm_nt(
    const u16* __restrict__ A, const u16* __restrict__ B,
    size_t strideA, size_t strideB, int lda, int ldb, int K,
    u16* __restrict__ o0, float* __restrict__ fo,
    const float* __restrict__ bias, const float* __restrict__ xres)
{
    __shared__ u16 As[128 * 64];
    __shared__ u16 Bs[128 * 64];

    const int tid   = threadIdx.x;
    const int lane  = tid & 63;
    const int wave  = tid >> 6;
    const int wm    = (wave >> 1) * 64;
    const int wn    = (wave & 1) * 64;
    const int l31   = lane & 31;
    const int khalf = lane >> 5;
    const int b     = blockIdx.z;

    const u16* Ab = A + (size_t)b * strideA + (size_t)blockIdx.y * 128 * lda;
    const u16* Bb = B + (size_t)b * strideB + (size_t)blockIdx.x * 128 * ldb;

    const int srow = lane >> 3;
    const int sc   = lane & 7;
    const int rkey = (l31 & 7) ^ ((l31 >> 2) & 7);

    f32x16 acc[2][2] = {};

    for (int k0 = 0; k0 < K; k0 += 64) {
        __syncthreads();
        #pragma unroll
        for (int s = 0; s < 4; s++) {
            const int r   = wave * 32 + s * 8 + srow;
            const int key = srow ^ ((2 * s + (srow >> 2)) & 7);
            GLDS16(Ab + (size_t)r * lda + k0 + ((sc ^ key) * 8),
                   As + r * 64 + sc * 8);
            GLDS16(Bb + (size_t)r * ldb + k0 + ((sc ^ key) * 8),
                   Bs + r * 64 + sc * 8);
        }
        __syncthreads();

        #pragma unroll
        for (int ks = 0; ks < 4; ks++) {
            const int slot = ((ks * 2 + khalf) ^ rkey) * 8;
            bf16x8 af[2], bfr[2];
            #pragma unroll
            for (int i = 0; i < 2; i++)
                af[i] = *(const bf16x8*)(As + (wm + i * 32 + l31) * 64 + slot);
            #pragma unroll
            for (int j = 0; j < 2; j++)
                bfr[j] = *(const bf16x8*)(Bs + (wn + j * 32 + l31) * 64 + slot);
            #pragma unroll
            for (int i = 0; i < 2; i++)
                #pragma unroll
                for (int j = 0; j < 2; j++)
                    acc[i][j] = __builtin_amdgcn_mfma_f32_32x32x16_bf16(
                        af[i], bfr[j], acc[i][j], 0, 0, 0);
        }
    }

    const int m_base = blockIdx.y * 128 + wm + 4 * khalf;
    const int n_base = blockIdx.x * 128 + wn + l31;

    #pragma unroll
    for (int i = 0; i < 2; i++) {
        #pragma unroll
        for (int j = 0; j < 2; j++) {
            const int n = n_base + j * 32;
            float bv = 0.f;
            if (MODE == 3) bv = bias[n];
            #pragma unroll
            for (int g = 0; g < 4; g++) {
                const int m = m_base + i * 32 + 8 * g;
                const float a0 = acc[i][j][4 * g]     + bv;
                const float a1 = acc[i][j][4 * g + 1] + bv;
                const float a2 = acc[i][j][4 * g + 2] + bv;
                const float a3 = acc[i][j][4 * g + 3] + bv;
                if (MODE == 2) {             // h2[b][t=n][c=m] bf16
                    ushort4 hv = {f2bf(a0), f2bf(a1), f2bf(a2), f2bf(a3)};
                    *(ushort4*)(o0 + ((size_t)b * 1024 + n) * 512 + m) = hv;
                } else {                     // proj + bias + residual, [B,C,T]
                    const size_t off = ((size_t)b * 512 + n) * 1024 + m;
                    const float4 xv = *(const float4*)(xres + off);
                    float4 ov = {a0 + xv.x, a1 + xv.y, a2 + xv.z, a3 + xv.w};
                    *(float4*)(fo + off) = ov;
                }
            }
        }
    }
}

// ---------------------------------------------------------------------------
extern "C" void kernel_launch(void* const* d_in, const int* in_sizes, int n_in,
                              void* d_out, int out_size, void* d_ws, size_t ws_size,
                              hipStream_t stream)
{
    const float* x     = (const float*)d_in[0];
    const float* gamma = (const float*)d_in[1];
    const float* beta  = (const float*)d_in[2];
    const float* Wq    = (const float*)d_in[3];
    const float* bq    = (const float*)d_in[4];
    const float* Wk    = (const float*)d_in[5];
    const float* bk    = (const float*)d_in[6];
    const float* Wv    = (const float*)d_in[7];
    const float* bv    = (const float*)d_in[8];
    const float* Wp    = (const float*)d_in[9];
    const float* bp    = (const float*)d_in[10];

    char* ws = (char*)d_ws;
    u16*   Wqkv   = (u16*)(ws + 0);           //  1,572,864 B
    u16*   Wpb    = (u16*)(ws + 1572864);     //    524,288 B
    float* bqkv   = (float*)(ws + 2097152);   //      8,192 B
    u16*   ht     = (u16*)(ws + 2105344);     // 16,777,216 B (reused as h2)
    u16*   kt     = (u16*)(ws + 18882560);    // 16,777,216 B
    u16*   vv     = (u16*)(ws + 35659776);    // 16,777,216 B
    u16*   scores = (u16*)(ws + 52436992);    // 33,554,432 B bf16
    // total ws: 85,991,424 B
    u16*   qt  = (u16*)d_out;   // scratch: q [B,T,C] bf16 (16.8MB of 33.5MB)
    u16*   h2  = ht;
    float* out = (float*)d_out;

    convert_kernel<<<4096, 256, 0, stream>>>(Wq, Wk, Wv, Wp, bq, bk, bv,
                                             Wqkv, Wpb, bqkv);
    gn_kernel<<<dim3(32, 16), 256, 0, stream>>>(x, gamma, beta, ht);

    // GEMM1 qkv: M=1024(T) N=1536(3C) K=512 ; A=ht[B,T,C], B=Wqkv[3C,C]
    gemm_wide<0><<<dim3(6, 8, 16), 256, 0, stream>>>(
        ht, Wqkv, 524288, 0, 512, 512, 512,
        qt, kt, vv, bqkv);

    // GEMM2 scores: M=1024(S) N=1024(T) K=512 ; A=kt, B=qt (scale pre-folded)
    gemm_wide<1><<<dim3(4, 8, 16), 256, 0, stream>>>(
        kt, qt, 524288, 524288, 512, 512, 512,
        scores, nullptr, nullptr, nullptr);

    softmax_kernel<<<4096, 256, 0, stream>>>(scores);

    // GEMM3 pv: M=512(C) N=1024(T) K=1024 ; A=v[C,S], B=P[T,S] compact bf16
    gemm_nt<2><<<dim3(8, 4, 16), 256, 0, stream>>>(
        vv, scores, 524288, 1048576, 1024, 1024, 1024,
        h2, nullptr, nullptr, nullptr);

    // GEMM4 proj+residual: M=1024(T) N=512 K=512 ; A=h2[B,T,C], B=Wp
    gemm_nt<3><<<dim3(4, 8, 16), 256, 0, stream>>>(
        h2, Wpb, 524288, 0, 512, 512, 512,
        nullptr, out, bp, x);
}